// Round 1
// baseline (24.125 us; speedup 1.0000x reference)
//
#include <hip/hip_runtime.h>
#include <cstddef>

// FTRL-FM forward, MI355X.
// B=4096 samples, K=50 active features/sample, F=1e6 features, M=32 factors.
// One 64-lane wave per sample:
//   lane = kp*8 + m4 ; kp in [0,8) = feature slot, m4 in [0,8) = float4 within row.
// Each iteration processes 8 feature rows; each row read as 8 lanes x float4 = 128B.

namespace {
constexpr int KF = 50;
constexpr int MF = 32;

__device__ __forceinline__ float ftrl_w(float z, float n, float l1, float l2,
                                        float ss /*sign scale*/) {
  // alpha = 0.1 (both orders), beta = 1.0
  float sgn = (z >= 0.f) ? 1.f : -1.f;
  float denom = (1.0f + sqrtf(n)) * 10.0f + l2;
  float w = (sgn * ss - z) / denom;
  return (fabsf(z) <= l1) ? 0.f : w;
}
} // namespace

__global__ __launch_bounds__(256) void ftrl_fm_kernel(
    const int* __restrict__ x_idx,
    const float* __restrict__ z1t, const float* __restrict__ n1t,
    const float* __restrict__ z2t, const float* __restrict__ n2t,
    float* __restrict__ out, int B) {
  const int wave_in_block = threadIdx.x >> 6;
  const int b = blockIdx.x * (blockDim.x >> 6) + wave_in_block;
  if (b >= B) return;
  const int lane = threadIdx.x & 63;
  const int* row = x_idx + b * KF;

  // Each lane < 50 owns one feature index; also used as the shfl-broadcast source.
  const int myidx = row[lane < KF ? lane : 0];

  // ---- 1st order: lane k computes w1(k) ----
  float lin = 0.f;
  if (lane < KF) {
    float z = z1t[myidx];
    float n = n1t[myidx];
    lin = ftrl_w(z, n, 0.05f, 0.05f, 0.05f);  // l1_1, l2_1, sign_scale=l1_1
  }

  // ---- 2nd order ----
  const int m4 = lane & 7;   // which float4 of the 32-float row
  const int kp = lane >> 3;  // which of 8 feature slots this iteration
  float4 s = make_float4(0.f, 0.f, 0.f, 0.f);  // partial s[m] for this kp-group
  float sumsq = 0.f;

#pragma unroll
  for (int kk = 0; kk < 7; ++kk) {
    const int k = kk * 8 + kp;
    const bool act = (k < KF);                 // runtime-divergent only at kk==6
    const int idx = __shfl(myidx, act ? k : 0, 64);
    if (act) {
      const float4 z = *((const float4*)(z2t + (size_t)idx * MF) + m4);
      const float4 n = *((const float4*)(n2t + (size_t)idx * MF) + m4);
      float w;
      w = ftrl_w(z.x, n.x, 0.05f, 1.0f, 0.05f); s.x += w; sumsq += w * w;
      w = ftrl_w(z.y, n.y, 0.05f, 1.0f, 0.05f); s.y += w; sumsq += w * w;
      w = ftrl_w(z.z, n.z, 0.05f, 1.0f, 0.05f); s.z += w; sumsq += w * w;
      w = ftrl_w(z.w, n.w, 0.05f, 1.0f, 0.05f); s.w += w; sumsq += w * w;
    }
  }

  // Combine s across the 8 kp-groups: xor-reduce over lane bits 3..5.
#pragma unroll
  for (int off = 8; off < 64; off <<= 1) {
    s.x += __shfl_xor(s.x, off, 64);
    s.y += __shfl_xor(s.y, off, 64);
    s.z += __shfl_xor(s.z, off, 64);
    s.w += __shfl_xor(s.w, off, 64);
  }

  // Per-lane partial of out[b]:
  //  - lin: distinct per lane (sum over wave = linear term)
  //  - ||s||^2: each m appears on 8 lanes -> 0.5 * sum_m s^2 == (1/16) * sum_lanes dot(s,s)
  //  - sumsq: distinct per lane, weight -0.5
  float v = lin
          + (s.x * s.x + s.y * s.y + s.z * s.z + s.w * s.w) * (1.0f / 16.0f)
          - 0.5f * sumsq;

  // Full 64-lane sum.
#pragma unroll
  for (int off = 1; off < 64; off <<= 1)
    v += __shfl_xor(v, off, 64);

  if (lane == 0) out[b] = v;
}

extern "C" void kernel_launch(void* const* d_in, const int* in_sizes, int n_in,
                              void* d_out, int out_size, void* d_ws, size_t ws_size,
                              hipStream_t stream) {
  const int*   x_idx = (const int*)d_in[0];
  const float* z1t   = (const float*)d_in[1];
  const float* n1t   = (const float*)d_in[2];
  const float* z2t   = (const float*)d_in[3];
  const float* n2t   = (const float*)d_in[4];
  float* out = (float*)d_out;

  const int B = out_size;                 // one scalar per sample
  const int waves_per_block = 4;          // 256 threads = 4 waves = 4 samples
  const int grid = (B + waves_per_block - 1) / waves_per_block;
  ftrl_fm_kernel<<<grid, 256, 0, stream>>>(x_idx, z1t, n1t, z2t, n2t, out, B);
}

// Round 2
// 21.583 us; speedup vs baseline: 1.1178x; 1.1178x over previous
//
#include <hip/hip_runtime.h>
#include <cstddef>

// FTRL-FM forward, MI355X. B=4096, K=50, F=1e6, M=32.
// One 256-thread block (4 waves) per sample.
// Thread layout: wave = tid>>6, lane = tid&63, m4 = lane&7 (float4 within the
// 32-float row), g = wave*8 + (lane>>3) = global feature slot in [0,32).
// Each thread handles slots {g, g+32} (second predicated by g<18), reading each
// row as 8 lanes x float4 = one 128B coalesced segment from z2 and n2.

namespace {
constexpr int KF = 50;
constexpr int MF = 32;

__device__ __forceinline__ float ftrl_w(float z, float n, float l1, float l2,
                                        float ss /*sign scale*/) {
  // alpha = 0.1 (both orders), beta = 1.0 -> denom = (1+sqrt(n))/0.1 + l2
  float sgn = (z >= 0.f) ? 1.f : -1.f;
  float denom = (1.0f + sqrtf(n)) * 10.0f + l2;
  float w = (sgn * ss - z) / denom;
  return (fabsf(z) <= l1) ? 0.f : w;
}

__device__ __forceinline__ float dot4(const float4& a, const float4& b) {
  return a.x * b.x + a.y * b.y + a.z * b.z + a.w * b.w;
}
} // namespace

__global__ __launch_bounds__(256) void ftrl_fm_kernel(
    const int* __restrict__ x_idx,
    const float* __restrict__ z1t, const float* __restrict__ n1t,
    const float* __restrict__ z2t, const float* __restrict__ n2t,
    float* __restrict__ out) {
  const int b = blockIdx.x;
  const int tid = threadIdx.x;
  const int wave = tid >> 6;
  const int lane = tid & 63;
  const int m4 = lane & 7;
  const int g = wave * 8 + (lane >> 3);  // [0,32)

  const int* __restrict__ row = x_idx + b * KF;

  // ---- issue ALL global loads up front, unconditionally ----
  const int idx0 = row[g];
  const int k1 = g + 32;
  const bool act1 = (k1 < KF);
  const int idx1 = row[act1 ? k1 : 0];          // dummy row[0] when inactive
  const float actf = act1 ? 1.f : 0.f;

  const float4 z0 = *((const float4*)(z2t + (size_t)idx0 * MF) + m4);
  const float4 n0 = *((const float4*)(n2t + (size_t)idx0 * MF) + m4);
  const float4 z1 = *((const float4*)(z2t + (size_t)idx1 * MF) + m4);
  const float4 n1 = *((const float4*)(n2t + (size_t)idx1 * MF) + m4);

  // 1st order: threads 0..49 each handle one feature
  float lin = 0.f;
  if (tid < KF) {
    const int i1 = row[tid];
    lin = ftrl_w(z1t[i1], n1t[i1], 0.05f, 0.05f, 0.05f);
  }

  // ---- 2nd-order weights ----
  float4 s;
  float sumsq;
  {
    float wx = ftrl_w(z0.x, n0.x, 0.05f, 1.0f, 0.05f);
    float wy = ftrl_w(z0.y, n0.y, 0.05f, 1.0f, 0.05f);
    float wz = ftrl_w(z0.z, n0.z, 0.05f, 1.0f, 0.05f);
    float ww = ftrl_w(z0.w, n0.w, 0.05f, 1.0f, 0.05f);
    s = make_float4(wx, wy, wz, ww);
    sumsq = wx * wx + wy * wy + wz * wz + ww * ww;
  }
  {
    float wx = actf * ftrl_w(z1.x, n1.x, 0.05f, 1.0f, 0.05f);
    float wy = actf * ftrl_w(z1.y, n1.y, 0.05f, 1.0f, 0.05f);
    float wz = actf * ftrl_w(z1.z, n1.z, 0.05f, 1.0f, 0.05f);
    float ww = actf * ftrl_w(z1.w, n1.w, 0.05f, 1.0f, 0.05f);
    s.x += wx; s.y += wy; s.z += wz; s.w += ww;
    sumsq += wx * wx + wy * wy + wz * wz + ww * ww;
  }

  // ---- wave-level combine of s across the 8 kp-groups (lane bits 3..5) ----
#pragma unroll
  for (int off = 8; off < 64; off <<= 1) {
    s.x += __shfl_xor(s.x, off, 64);
    s.y += __shfl_xor(s.y, off, 64);
    s.z += __shfl_xor(s.z, off, 64);
    s.w += __shfl_xor(s.w, off, 64);
  }

  __shared__ float4 sArr[4][8];
  __shared__ float partial[4];
  if (lane < 8) sArr[wave][lane] = s;   // lane == m4 here

  // scalar partials: lin (per-thread) and -0.5*sumsq (per-thread, each (k,m)
  // element counted exactly once across the block)
  float v = lin - 0.5f * sumsq;
#pragma unroll
  for (int off = 1; off < 64; off <<= 1)
    v += __shfl_xor(v, off, 64);
  if (lane == 0) partial[wave] = v;

  __syncthreads();

  if (tid == 0) {
    float acc = partial[0] + partial[1] + partial[2] + partial[3];
    float sq = 0.f;
#pragma unroll
    for (int m = 0; m < 8; ++m) {
      float4 t = sArr[0][m];
      t.x += sArr[1][m].x + sArr[2][m].x + sArr[3][m].x;
      t.y += sArr[1][m].y + sArr[2][m].y + sArr[3][m].y;
      t.z += sArr[1][m].z + sArr[2][m].z + sArr[3][m].z;
      t.w += sArr[1][m].w + sArr[2][m].w + sArr[3][m].w;
      sq += dot4(t, t);
    }
    out[b] = acc + 0.5f * sq;
  }
}

extern "C" void kernel_launch(void* const* d_in, const int* in_sizes, int n_in,
                              void* d_out, int out_size, void* d_ws, size_t ws_size,
                              hipStream_t stream) {
  const int*   x_idx = (const int*)d_in[0];
  const float* z1t   = (const float*)d_in[1];
  const float* n1t   = (const float*)d_in[2];
  const float* z2t   = (const float*)d_in[3];
  const float* n2t   = (const float*)d_in[4];
  float* out = (float*)d_out;

  const int B = out_size;  // 4096 samples, one block each
  ftrl_fm_kernel<<<B, 256, 0, stream>>>(x_idx, z1t, n1t, z2t, n2t, out);
}